// Round 1
// baseline (569.046 us; speedup 1.0000x reference)
//
#include <hip/hip_runtime.h>

typedef _Float16 h8v __attribute__((ext_vector_type(8)));
typedef float    f4v __attribute__((ext_vector_type(4)));

#define MFMA16(a,b,c) __builtin_amdgcn_mfma_f32_16x16x32_f16((a),(b),(c),0,0,0)
#define NEGF (-1e30f)

#define MEM 1000
#define KEY 64
#define VAL 128
#define DIN 512
#define BS  512
#define BQ  65536

// ---------------------------------------------------------------------------
// prep: fp16 transposed weights, top-k ranks, zero loss accumulator
// ---------------------------------------------------------------------------
__global__ void k_prep(const float* __restrict__ baseW, const float* __restrict__ kpW,
                       const float* __restrict__ c1W, const float* __restrict__ c2W,
                       const float* __restrict__ age,
                       _Float16* __restrict__ baseWt, _Float16* __restrict__ kpWt,
                       _Float16* __restrict__ c1Wt, _Float16* __restrict__ c2Wt,
                       int* __restrict__ ranks, float* __restrict__ out0)
{
  long id = (long)blockIdx.x * 256 + threadIdx.x;
  if (id < 32768) {                       // baseWt[n][k] = baseW[k][n], 64x512
    long n = id >> 9, k = id & 511;
    baseWt[id] = (_Float16)baseW[k * 64 + n];
  } else if (id < 36864) {                // kpWt[n][k], 64x64
    long i = id - 32768, n = i >> 6, k = i & 63;
    kpWt[i] = (_Float16)kpW[k * 64 + n];
  } else if (id < 61440) {                // c1Wt[n][k], 128x192
    long i = id - 36864, n = i / 192, k = i % 192;
    c1Wt[i] = (_Float16)c1W[k * 128 + n];
  } else if (id < 69632) {                // c2Wt[n][k], 64x128
    long i = id - 61440, n = i >> 7, k = i & 127;
    c2Wt[i] = (_Float16)c2W[k * 64 + n];
  } else if (id < 70632) {                // rank[j] = # elements strictly "older" (larger age)
    int j = (int)(id - 69632);
    float aj = age[j];
    int r = 0;
    for (int i = 0; i < MEM; ++i) {
      float ai = age[i];
      r += (ai > aj) || (ai == aj && i < j);   // stable tie-break like lax.top_k
    }
    ranks[j] = r;
  } else if (id == 70632) {
    *out0 = 0.f;                          // loss accumulator
  }
}

// support_feat = support_x @ base_W + base_b   [512,64]
__global__ void k_sfeat(const float* __restrict__ sx, const float* __restrict__ W,
                        const float* __restrict__ bb, float* __restrict__ sf)
{
  const int m = blockIdx.x, n = threadIdx.x;
  const float* xr = sx + (size_t)m * DIN;
  float acc = bb[n];
  for (int k = 0; k < DIN; ++k) acc += xr[k] * W[(size_t)k * KEY + n];
  sf[m * KEY + n] = acc;
}

// proj_vals = support_y @ vp_W + vp_b   [512,128]
__global__ void k_pvals(const float* __restrict__ sy, const float* __restrict__ W,
                        const float* __restrict__ bb, float* __restrict__ pv)
{
  const int m = blockIdx.x, n = threadIdx.x;
  const float* yr = sy + (size_t)m * VAL;
  float acc = bb[n];
  for (int k = 0; k < VAL; ++k) acc += yr[k] * W[(size_t)k * VAL + n];
  pv[m * VAL + n] = acc;
}

// proj_keys = support_feat @ kp_W + kp_b   [512,64]
__global__ void k_pkeys(const float* __restrict__ sf, const float* __restrict__ W,
                        const float* __restrict__ bb, float* __restrict__ pk)
{
  const int m = blockIdx.x, n = threadIdx.x;
  const float* fr = sf + (size_t)m * KEY;
  float acc = bb[n];
  for (int k = 0; k < KEY; ++k) acc += fr[k] * W[(size_t)k * KEY + n];
  pk[m * KEY + n] = acc;
}

// keysH[j][k] fp16, rows 1000..1023 zero-padded
__global__ void k_buildK(const int* __restrict__ ranks, const float* __restrict__ pk,
                         const float* __restrict__ memK, _Float16* __restrict__ keysH)
{
  const int j = blockIdx.x, t = threadIdx.x;    // grid 1024 x 64
  float v = 0.f;
  if (j < MEM) {
    int rk = ranks[j];
    v = (rk < BS) ? pk[(size_t)rk * KEY + t] : memK[(size_t)j * KEY + t];
  }
  keysH[(size_t)j * KEY + t] = (_Float16)v;
}

// valT[n][j] fp16 (transposed values), cols 1000..1023 zero-padded
__global__ void k_buildV(const int* __restrict__ ranks, const float* __restrict__ pv,
                         const float* __restrict__ memV, _Float16* __restrict__ valT)
{
  const int n = blockIdx.x, t = threadIdx.x;    // grid 128 x 256
  for (int jj = 0; jj < 4; ++jj) {
    int j = jj * 256 + t;
    float v = 0.f;
    if (j < MEM) {
      int rk = ranks[j];
      v = (rk < BS) ? pv[(size_t)rk * VAL + n] : memV[(size_t)j * VAL + n];
    }
    valT[(size_t)n * 1024 + j] = (_Float16)v;
  }
}

// ---------------------------------------------------------------------------
// fused query pipeline: one wave (64 threads) owns 32 queries end-to-end
// ---------------------------------------------------------------------------
__device__ __forceinline__ h8v cvt8(const float* p)
{
  float4 u = *(const float4*)p;
  float4 v = *(const float4*)(p + 4);
  h8v a;
  a[0] = (_Float16)u.x; a[1] = (_Float16)u.y; a[2] = (_Float16)u.z; a[3] = (_Float16)u.w;
  a[4] = (_Float16)v.x; a[5] = (_Float16)v.y; a[6] = (_Float16)v.z; a[7] = (_Float16)v.w;
  return a;
}

__global__ __launch_bounds__(64) void k_main(
    const float* __restrict__ qx, const float* __restrict__ qy,
    const float* __restrict__ base_b, const float* __restrict__ kp_b,
    const float* __restrict__ c1_b, const float* __restrict__ c2_b,
    const float* __restrict__ c3W, const float* __restrict__ c3b,
    const _Float16* __restrict__ baseWt, const _Float16* __restrict__ kpWt,
    const _Float16* __restrict__ c1Wt, const _Float16* __restrict__ c2Wt,
    const _Float16* __restrict__ keysH, const _Float16* __restrict__ valT,
    float* __restrict__ dout)
{
  // LDS: row strides padded (64->72, 128->136 halves) to break bank pile-up
  __shared__ __align__(16) char smem[26624];
  _Float16* qf_s  = (_Float16*)(smem);           // 32 x 72  (4608 B)
  _Float16* pq_s  = (_Float16*)(smem + 4608);    // 32 x 72  (h2 alias)
  _Float16* P_s   = (_Float16*)(smem + 9216);    // 32 x 136 (h1 alias)
  _Float16* ret_s = (_Float16*)(smem + 17920);   // 32 x 136

  const int lane = threadIdx.x;
  const int quad = lane >> 4;
  const int l15  = lane & 15;
  const int q0   = blockIdx.x * 32;

  float* out_pred = dout + 1;
  float* out_ret  = dout + 1 + BQ;

  const f4v fz = {0.f, 0.f, 0.f, 0.f};

  // ---------------- query_feat = x @ base_W + b ----------------
  f4v qa[2][4];
  #pragma unroll
  for (int rt = 0; rt < 2; ++rt)
    #pragma unroll
    for (int f = 0; f < 4; ++f) qa[rt][f] = fz;

  const float* xr0 = qx + (size_t)(q0 + l15) * DIN;
  const float* xr1 = qx + (size_t)(q0 + 16 + l15) * DIN;

  #pragma unroll 4
  for (int ks = 0; ks < 16; ++ks) {
    const int k0 = ks * 32 + quad * 8;
    h8v a0 = cvt8(xr0 + k0);
    h8v a1 = cvt8(xr1 + k0);
    #pragma unroll
    for (int f = 0; f < 4; ++f) {
      h8v b = *(const h8v*)(baseWt + (size_t)(f * 16 + l15) * DIN + k0);
      qa[0][f] = MFMA16(a0, b, qa[0][f]);
      qa[1][f] = MFMA16(a1, b, qa[1][f]);
    }
  }
  #pragma unroll
  for (int f = 0; f < 4; ++f) {
    float bb = base_b[f * 16 + l15];
    #pragma unroll
    for (int rt = 0; rt < 2; ++rt)
      #pragma unroll
      for (int r = 0; r < 4; ++r) {
        int row = rt * 16 + quad * 4 + r;
        qf_s[row * 72 + f * 16 + l15] = (_Float16)(qa[rt][f][r] + bb);
      }
  }

  // ---------------- proj_q = qf @ kp_W + b ----------------
  f4v pa[2][4];
  #pragma unroll
  for (int rt = 0; rt < 2; ++rt)
    #pragma unroll
    for (int f = 0; f < 4; ++f) pa[rt][f] = fz;

  #pragma unroll
  for (int ks = 0; ks < 2; ++ks) {
    const int k0 = ks * 32 + quad * 8;
    h8v a0 = *(const h8v*)&qf_s[l15 * 72 + k0];
    h8v a1 = *(const h8v*)&qf_s[(16 + l15) * 72 + k0];
    #pragma unroll
    for (int f = 0; f < 4; ++f) {
      h8v b = *(const h8v*)(kpWt + (size_t)(f * 16 + l15) * KEY + k0);
      pa[0][f] = MFMA16(a0, b, pa[0][f]);
      pa[1][f] = MFMA16(a1, b, pa[1][f]);
    }
  }
  #pragma unroll
  for (int f = 0; f < 4; ++f) {
    float bb = kp_b[f * 16 + l15];
    #pragma unroll
    for (int rt = 0; rt < 2; ++rt)
      #pragma unroll
      for (int r = 0; r < 4; ++r) {
        int row = rt * 16 + quad * 4 + r;
        pq_s[row * 72 + f * 16 + l15] = (_Float16)(pa[rt][f][r] + bb);
      }
  }

  // ---------------- attention: online softmax over 8 chunks of 128 mem ----
  float rm[2][4], rl[2][4];
  #pragma unroll
  for (int rt = 0; rt < 2; ++rt)
    #pragma unroll
    for (int r = 0; r < 4; ++r) { rm[rt][r] = NEGF; rl[rt][r] = 0.f; }

  f4v O[2][8];
  #pragma unroll
  for (int rt = 0; rt < 2; ++rt)
    #pragma unroll
    for (int v = 0; v < 8; ++v) O[rt][v] = fz;

  #pragma unroll 1
  for (int c = 0; c < 8; ++c) {
    #pragma unroll 1
    for (int rt = 0; rt < 2; ++rt) {
      f4v S[8];
      #pragma unroll
      for (int f = 0; f < 8; ++f) S[f] = fz;

      #pragma unroll
      for (int ks = 0; ks < 2; ++ks) {
        const int k0 = ks * 32 + quad * 8;
        h8v a = *(const h8v*)&pq_s[(rt * 16 + l15) * 72 + k0];
        #pragma unroll
        for (int f = 0; f < 8; ++f) {
          h8v b = *(const h8v*)(keysH + (size_t)(c * 128 + f * 16 + l15) * KEY + k0);
          S[f] = MFMA16(a, b, S[f]);
        }
      }
      // mask pad cols + chunk row-max
      float cm[4] = {NEGF, NEGF, NEGF, NEGF};
      #pragma unroll
      for (int f = 0; f < 8; ++f) {
        const int col = c * 128 + f * 16 + l15;
        const bool ok = (col < MEM);
        #pragma unroll
        for (int r = 0; r < 4; ++r) {
          float s = ok ? S[f][r] : NEGF;
          S[f][r] = s;
          cm[r] = fmaxf(cm[r], s);
        }
      }
      #pragma unroll
      for (int r = 0; r < 4; ++r) {
        #pragma unroll
        for (int m = 1; m < 16; m <<= 1) cm[r] = fmaxf(cm[r], __shfl_xor(cm[r], m));
      }
      float al[4], ps[4] = {0.f, 0.f, 0.f, 0.f};
      #pragma unroll
      for (int r = 0; r < 4; ++r) {
        float mn = fmaxf(rm[rt][r], cm[r]);
        al[r] = __expf(rm[rt][r] - mn);
        rm[rt][r] = mn;
      }
      #pragma unroll
      for (int f = 0; f < 8; ++f)
        #pragma unroll
        for (int r = 0; r < 4; ++r) {
          float p = __expf(S[f][r] - rm[rt][r]);
          S[f][r] = p;
          ps[r] += p;
        }
      #pragma unroll
      for (int r = 0; r < 4; ++r) {
        #pragma unroll
        for (int m = 1; m < 16; m <<= 1) ps[r] += __shfl_xor(ps[r], m);
        rl[rt][r] = rl[rt][r] * al[r] + ps[r];
      }
      // write P (A-operand layout) + rescale O
      #pragma unroll
      for (int f = 0; f < 8; ++f)
        #pragma unroll
        for (int r = 0; r < 4; ++r)
          P_s[(rt * 16 + quad * 4 + r) * 136 + f * 16 + l15] = (_Float16)S[f][r];
      #pragma unroll
      for (int v = 0; v < 8; ++v)
        #pragma unroll
        for (int r = 0; r < 4; ++r) O[rt][v][r] *= al[r];
    }
    // P @ V accumulate
    #pragma unroll
    for (int ks = 0; ks < 4; ++ks) {
      const int k0 = ks * 32 + quad * 8;
      h8v a0 = *(const h8v*)&P_s[l15 * 136 + k0];
      h8v a1 = *(const h8v*)&P_s[(16 + l15) * 136 + k0];
      #pragma unroll
      for (int v = 0; v < 8; ++v) {
        h8v b = *(const h8v*)(valT + (size_t)(v * 16 + l15) * 1024 + c * 128 + k0);
        O[0][v] = MFMA16(a0, b, O[0][v]);
        O[1][v] = MFMA16(a1, b, O[1][v]);
      }
    }
  }
  // retrieved = O / l  -> global fp32 + LDS fp16
  #pragma unroll
  for (int rt = 0; rt < 2; ++rt)
    #pragma unroll
    for (int v = 0; v < 8; ++v)
      #pragma unroll
      for (int r = 0; r < 4; ++r) {
        int row = rt * 16 + quad * 4 + r;
        int col = v * 16 + l15;
        float val = O[rt][v][r] / rl[rt][r];
        out_ret[(size_t)(q0 + row) * VAL + col] = val;
        ret_s[row * 136 + col] = (_Float16)val;
      }

  // ---------------- c1: relu([qf|ret] @ c1_W + b) ----------------
  _Float16* h1_s = P_s;   // P dead
  #pragma unroll 1
  for (int rt = 0; rt < 2; ++rt) {
    f4v H[8];
    #pragma unroll
    for (int f = 0; f < 8; ++f) H[f] = fz;
    #pragma unroll
    for (int ks = 0; ks < 6; ++ks) {
      const int k0 = ks * 32 + quad * 8;
      h8v a = (k0 < 64) ? *(const h8v*)&qf_s[(rt * 16 + l15) * 72 + k0]
                        : *(const h8v*)&ret_s[(rt * 16 + l15) * 136 + (k0 - 64)];
      #pragma unroll
      for (int f = 0; f < 8; ++f) {
        h8v b = *(const h8v*)(c1Wt + (size_t)(f * 16 + l15) * 192 + k0);
        H[f] = MFMA16(a, b, H[f]);
      }
    }
    #pragma unroll
    for (int f = 0; f < 8; ++f) {
      float bb = c1_b[f * 16 + l15];
      #pragma unroll
      for (int r = 0; r < 4; ++r)
        h1_s[(rt * 16 + quad * 4 + r) * 136 + f * 16 + l15] =
            (_Float16)fmaxf(0.f, H[f][r] + bb);
    }
  }

  // ---------------- c2: relu(h1 @ c2_W + b) ----------------
  _Float16* h2_s = pq_s;  // pq dead
  #pragma unroll 1
  for (int rt = 0; rt < 2; ++rt) {
    f4v G[4];
    #pragma unroll
    for (int f = 0; f < 4; ++f) G[f] = fz;
    #pragma unroll
    for (int ks = 0; ks < 4; ++ks) {
      const int k0 = ks * 32 + quad * 8;
      h8v a = *(const h8v*)&h1_s[(rt * 16 + l15) * 136 + k0];
      #pragma unroll
      for (int f = 0; f < 4; ++f) {
        h8v b = *(const h8v*)(c2Wt + (size_t)(f * 16 + l15) * 128 + k0);
        G[f] = MFMA16(a, b, G[f]);
      }
    }
    #pragma unroll
    for (int f = 0; f < 4; ++f) {
      float bb = c2_b[f * 16 + l15];
      #pragma unroll
      for (int r = 0; r < 4; ++r)
        h2_s[(rt * 16 + quad * 4 + r) * 72 + f * 16 + l15] =
            (_Float16)fmaxf(0.f, G[f][r] + bb);
    }
  }

  // ---------------- pred = h2 @ c3_W + b ; loss ----------------
  const int prow = lane >> 1, pj = lane & 1;   // 2 lanes per query row
  float s = 0.f;
  #pragma unroll
  for (int k = 0; k < 32; ++k) {
    int kk = pj * 32 + k;
    s += (float)h2_s[prow * 72 + kk] * c3W[kk];
  }
  s += __shfl_xor(s, 1);
  float pred = s + c3b[0];
  float diff = pred - qy[q0 + prow];
  if (pj == 0) out_pred[q0 + prow] = pred;
  float sq = diff * diff;                 // each row counted twice
  #pragma unroll
  for (int m = 1; m < 64; m <<= 1) sq += __shfl_xor(sq, m);
  if (lane == 0) atomicAdd(dout, sq * (1.0f / (2.0f * (float)BQ)));
}

// ---------------------------------------------------------------------------
extern "C" void kernel_launch(void* const* d_in, const int* in_sizes, int n_in,
                              void* d_out, int out_size, void* d_ws, size_t ws_size,
                              hipStream_t stream)
{
  const float* support_x = (const float*)d_in[0];
  const float* support_y = (const float*)d_in[1];
  const float* query_x   = (const float*)d_in[2];
  const float* query_y   = (const float*)d_in[3];
  const float* base_W    = (const float*)d_in[4];
  const float* base_b    = (const float*)d_in[5];
  const float* kp_W      = (const float*)d_in[6];
  const float* kp_b      = (const float*)d_in[7];
  const float* vp_W      = (const float*)d_in[8];
  const float* vp_b      = (const float*)d_in[9];
  const float* mem_keys  = (const float*)d_in[10];
  const float* mem_vals  = (const float*)d_in[11];
  const float* mem_age   = (const float*)d_in[12];
  const float* c1_W      = (const float*)d_in[13];
  const float* c1_b      = (const float*)d_in[14];
  const float* c2_W      = (const float*)d_in[15];
  const float* c2_b      = (const float*)d_in[16];
  const float* c3_W      = (const float*)d_in[17];
  const float* c3_b      = (const float*)d_in[18];

  char* w = (char*)d_ws;                       // ~1.01 MB used
  float*    sfeat  = (float*)(w + 0);          // 512x64  f32
  float*    pvals  = (float*)(w + 131072);     // 512x128 f32
  float*    pkeys  = (float*)(w + 393216);     // 512x64  f32
  int*      ranks  = (int*)  (w + 524288);     // 1000 i32
  _Float16* baseWt = (_Float16*)(w + 528384);  // 64x512
  _Float16* kpWt   = (_Float16*)(w + 593920);  // 64x64
  _Float16* c1Wt   = (_Float16*)(w + 602112);  // 128x192
  _Float16* c2Wt   = (_Float16*)(w + 651264);  // 64x128
  _Float16* keysH  = (_Float16*)(w + 667648);  // 1024x64 (padded)
  _Float16* valT   = (_Float16*)(w + 798720);  // 128x1024 (padded)

  float* out = (float*)d_out;

  hipLaunchKernelGGL(k_prep,   dim3(276),  dim3(256), 0, stream,
                     base_W, kp_W, c1_W, c2_W, mem_age,
                     baseWt, kpWt, c1Wt, c2Wt, ranks, out);
  hipLaunchKernelGGL(k_sfeat,  dim3(512),  dim3(64),  0, stream,
                     support_x, base_W, base_b, sfeat);
  hipLaunchKernelGGL(k_pvals,  dim3(512),  dim3(128), 0, stream,
                     support_y, vp_W, vp_b, pvals);
  hipLaunchKernelGGL(k_pkeys,  dim3(512),  dim3(64),  0, stream,
                     sfeat, kp_W, kp_b, pkeys);
  hipLaunchKernelGGL(k_buildK, dim3(1024), dim3(64),  0, stream,
                     ranks, pkeys, mem_keys, keysH);
  hipLaunchKernelGGL(k_buildV, dim3(128),  dim3(256), 0, stream,
                     ranks, pvals, mem_vals, valT);
  hipLaunchKernelGGL(k_main,   dim3(BQ / 32), dim3(64), 0, stream,
                     query_x, query_y, base_b, kp_b, c1_b, c2_b, c3_W, c3_b,
                     baseWt, kpWt, c1Wt, c2Wt, keysH, valT, out);
}